// Round 6
// baseline (307.140 us; speedup 1.0000x reference)
//
#include <hip/hip_runtime.h>

#define NK  256   // IN == OUT == 256
#define LDN 264   // LDS row stride in ushort (528B -> 2-way bank aliasing, free per m136)

typedef __attribute__((ext_vector_type(8))) short bf16x8;
typedef __attribute__((ext_vector_type(4))) float f32x4;

union BF8 { bf16x8 v; ushort u[8]; uint4 q; };

__device__ inline ushort f2bf(float f) {
    // round-to-nearest-even fp32 -> bf16 (inputs are finite normals)
    uint u = __float_as_uint(f);
    u += 0x7FFFu + ((u >> 16) & 1u);
    return (ushort)(u >> 16);
}

// ---- pre-kernel: binarize W once -> workspace as bf16 {0, 1.0} --------------
__global__ void binarize_w(const float* __restrict__ w, ushort* __restrict__ wb)
{
    int i = blockIdx.x * 256 + threadIdx.x;        // 8192 threads x 8 elems
    const float4* wp = (const float4*)(w + (size_t)i * 8);
    float4 w0 = wp[0], w1 = wp[1];
    uint4 pk;
    pk.x = (w0.x > 0.8f ? 0x00003F80u : 0u) | (w0.y > 0.8f ? 0x3F800000u : 0u);
    pk.y = (w0.z > 0.8f ? 0x00003F80u : 0u) | (w0.w > 0.8f ? 0x3F800000u : 0u);
    pk.z = (w1.x > 0.8f ? 0x00003F80u : 0u) | (w1.y > 0.8f ? 0x3F800000u : 0u);
    pk.w = (w1.z > 0.8f ? 0x00003F80u : 0u) | (w1.w > 0.8f ? 0x3F800000u : 0u);
    *(uint4*)(wb + (size_t)i * 8) = pk;
}

// ---- main kernel: 1024 thr (16 waves), grid=256 -> exactly 1 block/CU, ------
// single round. Full 132 KB B resident; 2 M-tiles of 256 rows per block.
// KEY FIX: __syncthreads drains vmcnt(0) (compiler emits full waitcnt before
// s_barrier), which serialized every round so far: the A-load burst was force-
// drained at the staging barrier. Replace with raw s_barrier + lgkmcnt(0)-only
// drain -> A0 loads genuinely stay in flight across the barrier.
// Store bursts stay sched_barrier-fenced (proven exact WRITE_SIZE in r5).
__global__ __launch_bounds__(1024, 4) void fused_binlinear(
    const float* __restrict__ x, const ushort* __restrict__ wb, float* __restrict__ out)
{
    __shared__ ushort Bs[256 * LDN];   // 132 KB -> 1 block/CU

    const int tid = threadIdx.x;
    const int wv  = tid >> 6;   // 0..15
    const int ln  = tid & 63;
    const int m   = ln & 15;   // MFMA m / n / col lane index
    const int q   = ln >> 4;   // MFMA k-quad / row-quad

    // block covers rows [blk*512, +512): tile0 = first 256, tile1 = second 256
    const size_t rowBase = (size_t)blockIdx.x * 512 + wv * 16;

    // ---- A0 loads issued first; with the raw barrier they truly fly ----
    const float4* xv0 = (const float4*)(x + (rowBase + m) * NK + q * 8);
    float4 a0[8], a1[8];
#pragma unroll
    for (int s = 0; s < 8; ++s) { a0[s] = xv0[s * 8]; a1[s] = xv0[s * 8 + 1]; }

    // ---- stage full binarized B (128 KB bf16, pure copy from L2-hot wb) ----
#pragma unroll
    for (int i = 0; i < 8; ++i) {
        int cc = i * 1024 + tid;         // 8-elem chunk id, 8192 total
        int n  = cc >> 5;                // 0..255
        int kc = cc & 31;
        *(uint4*)(&Bs[n * LDN + kc * 8]) =
            *(const uint4*)(wb + (size_t)n * NK + kc * 8);
    }

    // ---- raw barrier: drain LDS writes ONLY; A0 global loads stay in flight ----
    asm volatile("s_waitcnt lgkmcnt(0)" ::: "memory");
    __builtin_amdgcn_s_barrier();
    __builtin_amdgcn_sched_barrier(0);   // nothing moves across the barrier

    // ---- convert A0: lane holds A[m][k = s*32 + q*8 + j] (waits its own A0) ----
    bf16x8 fa[8];
#pragma unroll
    for (int s = 0; s < 8; ++s) {
        BF8 t;
        t.u[0] = f2bf(a0[s].x); t.u[1] = f2bf(a0[s].y);
        t.u[2] = f2bf(a0[s].z); t.u[3] = f2bf(a0[s].w);
        t.u[4] = f2bf(a1[s].x); t.u[5] = f2bf(a1[s].y);
        t.u[6] = f2bf(a1[s].z); t.u[7] = f2bf(a1[s].w);
        fa[s] = t.v;
    }

    // ---- issue A1 loads now: they fly under tile-0 MFMA + store drain ----
    const float4* xv1 = (const float4*)(x + (rowBase + 256 + m) * NK + q * 8);
#pragma unroll
    for (int s = 0; s < 8; ++s) { a0[s] = xv1[s * 8]; a1[s] = xv1[s * 8 + 1]; }

    // ---- tile 0 MFMA: 8 k-steps x 16 n-tiles; B row t*16+m, k = s*32+q*8 ----
    f32x4 acc[16];
#pragma unroll
    for (int t = 0; t < 16; ++t) acc[t] = (f32x4){0.f, 0.f, 0.f, 0.f};
#pragma unroll
    for (int s = 0; s < 8; ++s) {
#pragma unroll
        for (int t = 0; t < 16; ++t) {
            bf16x8 fb = *(const bf16x8*)(&Bs[(t * 16 + m) * LDN + s * 32 + q * 8]);
            acc[t] = __builtin_amdgcn_mfma_f32_16x16x32_bf16(fa[s], fb, acc[t], 0, 0, 0);
        }
    }

    // ---- tile 0: fused row-mean (C/D layout col=m, row=q*4+r) + fenced store ----
    float rs[4];
#pragma unroll
    for (int r = 0; r < 4; ++r) {
        float s = 0.f;
#pragma unroll
        for (int t = 0; t < 16; ++t) s += acc[t][r];
        rs[r] = s;
    }
#pragma unroll
    for (int r = 0; r < 4; ++r) {
        rs[r] += __shfl_xor(rs[r], 1, 64);
        rs[r] += __shfl_xor(rs[r], 2, 64);
        rs[r] += __shfl_xor(rs[r], 4, 64);
        rs[r] += __shfl_xor(rs[r], 8, 64);
        rs[r] *= (1.0f / 256.0f);
    }
    __builtin_amdgcn_sched_barrier(0);   // keep store burst contiguous
#pragma unroll
    for (int t = 0; t < 16; ++t) {
#pragma unroll
        for (int r = 0; r < 4; ++r) {
            out[(rowBase + q * 4 + r) * NK + t * 16 + m] = acc[t][r] - rs[r];
        }
    }
    __builtin_amdgcn_sched_barrier(0);   // stores issued; drain under tile 1

    // ---- tile 1: convert A1 (landed during tile-0 compute/stores) ----
#pragma unroll
    for (int s = 0; s < 8; ++s) {
        BF8 t;
        t.u[0] = f2bf(a0[s].x); t.u[1] = f2bf(a0[s].y);
        t.u[2] = f2bf(a0[s].z); t.u[3] = f2bf(a0[s].w);
        t.u[4] = f2bf(a1[s].x); t.u[5] = f2bf(a1[s].y);
        t.u[6] = f2bf(a1[s].z); t.u[7] = f2bf(a1[s].w);
        fa[s] = t.v;
    }

    // ---- tile 1 MFMA: B still resident in LDS, no staging, no barrier ----
#pragma unroll
    for (int t = 0; t < 16; ++t) acc[t] = (f32x4){0.f, 0.f, 0.f, 0.f};
#pragma unroll
    for (int s = 0; s < 8; ++s) {
#pragma unroll
        for (int t = 0; t < 16; ++t) {
            bf16x8 fb = *(const bf16x8*)(&Bs[(t * 16 + m) * LDN + s * 32 + q * 8]);
            acc[t] = __builtin_amdgcn_mfma_f32_16x16x32_bf16(fa[s], fb, acc[t], 0, 0, 0);
        }
    }

    // ---- tile 1: row-mean + fenced store burst ----
#pragma unroll
    for (int r = 0; r < 4; ++r) {
        float s = 0.f;
#pragma unroll
        for (int t = 0; t < 16; ++t) s += acc[t][r];
        rs[r] = s;
    }
#pragma unroll
    for (int r = 0; r < 4; ++r) {
        rs[r] += __shfl_xor(rs[r], 1, 64);
        rs[r] += __shfl_xor(rs[r], 2, 64);
        rs[r] += __shfl_xor(rs[r], 4, 64);
        rs[r] += __shfl_xor(rs[r], 8, 64);
        rs[r] *= (1.0f / 256.0f);
    }
    __builtin_amdgcn_sched_barrier(0);
#pragma unroll
    for (int t = 0; t < 16; ++t) {
#pragma unroll
        for (int r = 0; r < 4; ++r) {
            out[(rowBase + 256 + q * 4 + r) * NK + t * 16 + m] = acc[t][r] - rs[r];
        }
    }
}

extern "C" void kernel_launch(void* const* d_in, const int* in_sizes, int n_in,
                              void* d_out, int out_size, void* d_ws, size_t ws_size,
                              hipStream_t stream) {
    const float* x  = (const float*)d_in[0];   // [131072, 256] fp32
    const float* w  = (const float*)d_in[1];   // [256, 256] fp32
    float* out      = (float*)d_out;           // [131072, 256] fp32
    ushort* wbin    = (ushort*)d_ws;           // 128 KB bf16 binarized W
    const int M     = in_sizes[0] / NK;        // 131072

    binarize_w<<<32, 256, 0, stream>>>(w, wbin);             // 65536 elems / 8
    fused_binlinear<<<M / 512, 1024, 0, stream>>>(x, wbin, out);  // 256 blocks = 1/CU
}